// Round 3
// baseline (8333.619 us; speedup 1.0000x reference)
//
#include <hip/hip_runtime.h>
#include <math.h>

// SpatialGRU persistent-wavefront kernel. B=64, C=16, L=64, R=64, U=64, D=208.
// 64 persistent blocks, block = one grid row l; cells (l, r=0..63) sequential.
// Cross-block dep (top row) via agent-scope flag release/poll + LLC-coherent
// atomic row loads. left/diag state kept in per-block LDS (fp32).
// Phase A: [64 b x 448 kp] = hq[64x224] @ W^T   (bf16 MFMA 16x16x32)
// Phase B: [64 b x 64 u]   = P [64x224] @ U2^T  (P = rr.*hu | x)

typedef short s16x8 __attribute__((ext_vector_type(8)));
typedef float f32x4 __attribute__((ext_vector_type(4)));

#define ASTR 232                 // hq row stride (bf16 elems); 224 data + 8 pad
#define N_WF (28*7*512)          // shorts
#define N_UF (4*7*512)           // shorts
#define N_XT (4096*1024)         // shorts
#define SMEM_BYTES (64*ASTR*2 + 3*64*68*4 + 2*64*68*4)   // 116736 B

#define HFv(s,b,u)  HF[(((s)*64 + (b))*68) + (u)]

__device__ __forceinline__ unsigned short f2bf(float v) {
    unsigned int x = __float_as_uint(v);
    unsigned int r = (x + 0x7fffu + ((x >> 16) & 1u)) >> 16;
    return (unsigned short)r;
}
__device__ __forceinline__ unsigned int pack2(float a, float b) {
    return (unsigned int)f2bf(a) | ((unsigned int)f2bf(b) << 16);
}

// ---- prep: pack weights into MFMA B-fragment lane order ----
__global__ __launch_bounds__(256) void prep_pack(
    const float* __restrict__ wr_w, const float* __restrict__ wr_b,
    const float* __restrict__ wz_w, const float* __restrict__ wz_b,
    const float* __restrict__ wij_w, const float* __restrict__ U_w,
    unsigned short* __restrict__ WF, unsigned short* __restrict__ UF,
    float* __restrict__ BAf)
{
    int idx = blockIdx.x * 256 + threadIdx.x;
    if (idx < 28*7*64) {
        int frag = idx >> 6, lane = idx & 63;
        int nt = frag / 7, ks = frag % 7;
        int kp = nt*16 + (lane & 15);
        int kb = ks*32 + ((lane >> 4) << 3);
        #pragma unroll
        for (int e = 0; e < 8; ++e) {
            int k = kb + e;
            float v = 0.f;
            if (k < 208) {
                if (kp < 192) v = wr_w[kp*208 + k];
                else { int q = kp - 192; v = wz_w[((q & 3)*64 + (q >> 2))*208 + k]; }
            }
            WF[idx*8 + e] = f2bf(v);
        }
        return;
    }
    idx -= 28*7*64;
    if (idx < 4*7*64) {
        int frag = idx >> 6, lane = idx & 63;
        int t2 = frag / 7, ks = frag % 7;
        int u = t2*16 + (lane & 15);
        int kb = ks*32 + ((lane >> 4) << 3);
        #pragma unroll
        for (int e = 0; e < 8; ++e) {
            int k = kb + e;
            float v = 0.f;
            if (k < 192) v = U_w[u*192 + k];
            else if (k < 208) v = wij_w[u*16 + (k - 192)];
            UF[idx*8 + e] = f2bf(v);
        }
        return;
    }
    idx -= 4*7*64;
    if (idx < 512) {
        float v = 0.f;
        if (idx < 192) v = wr_b[idx];
        else if (idx < 448) { int q = idx - 192; v = wz_b[(q & 3)*64 + (q >> 2)]; }
        BAf[idx] = v;
    }
}

// ---- prep: transpose inputs (B,C,L,R) -> XT[(l,r)][(b,c)] bf16 ----
__global__ __launch_bounds__(256) void xpose(const float* __restrict__ inp,
                                             unsigned short* __restrict__ XT)
{
    __shared__ float tile[32][33];
    int bi = blockIdx.x;   // lr / 32
    int bj = blockIdx.y;   // bc / 32
    int tx = threadIdx.x & 31, ty = threadIdx.x >> 5;
    #pragma unroll
    for (int yy = 0; yy < 4; ++yy) {
        int bc = bj*32 + ty*4 + yy;
        tile[ty*4 + yy][tx] = inp[bc*4096 + bi*32 + tx];
    }
    __syncthreads();
    #pragma unroll
    for (int yy = 0; yy < 4; ++yy) {
        int lr = bi*32 + ty*4 + yy;
        XT[lr*1024 + bj*32 + tx] = f2bf(tile[tx][ty*4 + yy]);
    }
}

// ---- persistent wavefront ----
__global__ __launch_bounds__(512, 2) void gru_persist(
    const unsigned short* __restrict__ WF,
    const unsigned short* __restrict__ UF,
    const float* __restrict__ BAf,
    const unsigned short* __restrict__ XT,
    const float* __restrict__ wij_b,
    float* __restrict__ Hout,          // [l][r][b][u] fp32
    int* __restrict__ flags,           // [l][r]
    float* __restrict__ out)
{
    extern __shared__ char smem[];
    unsigned short* hq_s = (unsigned short*)smem;            // [64][ASTR] bf16
    float* HF = (float*)(smem + 64*ASTR*2);                  // [3][64][68]: ht/hl/hd fp32
    float* ZH_s = HF + 3*64*68;                              // [64][68]
    float* ZI_s = ZH_s + 64*68;                              // [64][68]

    const int tid = threadIdx.x;
    // XCD-swizzle: 8 consecutive rows per XCD (adjacent-row flag hops stay local)
    const int l = ((blockIdx.x & 7) << 3) | (blockIdx.x >> 3);

    // init: HF zero; hq K-pad cols [208,232) zero
    for (int i = tid; i < 3*64*68; i += 512) HF[i] = 0.f;
    for (int i = tid; i < 64*24; i += 512) { int b = i/24, c = 208 + (i % 24); hq_s[b*ASTR + c] = 0; }

    const int wv = tid >> 6, lane = tid & 63;
    const int col = lane & 15, rowq = (lane >> 4) << 2;
    const int sb = tid >> 3, su = (tid & 7) * 8;             // staging ownership
    const int nh = wv & 3, mh = wv >> 2;                     // phase A tile
    const int mt = wv >> 1, th = (wv & 1) * 2;               // phase B tile

    for (int r = 0; r < 64; ++r) {
        // ---- S0: wait for top row (l-1, r) ----
        if (l > 0 && tid == 0) {
            while (__hip_atomic_load(&flags[(l-1)*64 + r], __ATOMIC_RELAXED,
                                     __HIP_MEMORY_SCOPE_AGENT) == 0)
                __builtin_amdgcn_s_sleep(1);
            asm volatile("" ::: "memory");
        }
        __syncthreads();

        // ---- staging: hd <- old ht; ht <- row (l-1,r); hl <- own prev h; x ----
        {
            float oht[8], hl8[8], nht[8];
            #pragma unroll
            for (int e = 0; e < 8; ++e) oht[e] = HFv(0, sb, su + e);
            #pragma unroll
            for (int e = 0; e < 8; ++e) hl8[e] = HFv(1, sb, su + e);
            if (l > 0) {
                const float* Hrow = Hout + ((size_t)((l-1)*64 + r)) * 4096;
                #pragma unroll
                for (int e = 0; e < 8; ++e)
                    nht[e] = __uint_as_float(__hip_atomic_load(
                        (const unsigned int*)&Hrow[sb*64 + su + e],
                        __ATOMIC_RELAXED, __HIP_MEMORY_SCOPE_AGENT));
            } else {
                #pragma unroll
                for (int e = 0; e < 8; ++e) nht[e] = 0.f;
            }
            #pragma unroll
            for (int e = 0; e < 8; ++e) HFv(2, sb, su + e) = oht[e];
            #pragma unroll
            for (int e = 0; e < 8; ++e) HFv(0, sb, su + e) = nht[e];
            #pragma unroll
            for (int e = 0; e < 8; e += 2) {
                *(unsigned int*)&hq_s[sb*ASTR +       su + e] = pack2(nht[e], nht[e+1]); // ht
                *(unsigned int*)&hq_s[sb*ASTR +  64 + su + e] = pack2(hl8[e], hl8[e+1]); // hl
                *(unsigned int*)&hq_s[sb*ASTR + 128 + su + e] = pack2(oht[e], oht[e+1]); // hd
            }
            if (su < 16) {   // x: 2 threads per b row, 8 shorts each
                const unsigned short* xs = XT + ((size_t)(l*64 + r))*1024 + sb*16 + su;
                #pragma unroll
                for (int e = 0; e < 8; e += 2)
                    *(unsigned int*)&hq_s[sb*ASTR + 192 + su + e] = *(const unsigned int*)&xs[e];
            }
        }
        __syncthreads();

        // ---- phase A GEMM: 2 M-tiles x 7 N-tiles x 7 K ----
        f32x4 acc[7][2];
        #pragma unroll
        for (int t = 0; t < 7; ++t) { acc[t][0] = (f32x4){0,0,0,0}; acc[t][1] = (f32x4){0,0,0,0}; }
        #pragma unroll
        for (int ks = 0; ks < 7; ++ks) {
            s16x8 af0 = *(const s16x8*)&hq_s[(mh*32 + col)*ASTR + ks*32 + (rowq << 1)];
            s16x8 af1 = *(const s16x8*)&hq_s[(mh*32 + 16 + col)*ASTR + ks*32 + (rowq << 1)];
            #pragma unroll
            for (int t = 0; t < 7; ++t) {
                s16x8 bf = *(const s16x8*)&WF[(((nh*7 + t)*7 + ks)*64 + lane)*8];
                acc[t][0] = __builtin_amdgcn_mfma_f32_16x16x32_bf16(af0, bf, acc[t][0], 0, 0, 0);
                acc[t][1] = __builtin_amdgcn_mfma_f32_16x16x32_bf16(af1, bf, acc[t][1], 0, 0, 0);
            }
        }
        __syncthreads();

        // ---- activations: rr -> P (overwrite hq cols 0..191); z -> gates ----
        #pragma unroll
        for (int t = 0; t < 7; ++t) {
            const int kp = (nh*7 + t)*16 + col;
            const float bias = BAf[kp];
            const bool isrr = kp < 192;
            #pragma unroll
            for (int mti = 0; mti < 2; ++mti) {
                #pragma unroll
                for (int reg = 0; reg < 4; ++reg) {
                    const int b = (mh*2 + mti)*16 + rowq + reg;
                    const float val = acc[t][mti][reg] + bias;
                    if (isrr) {
                        float hu = (kp < 64)  ? HFv(1, b, kp)
                                 : (kp < 128) ? HFv(0, b, kp - 64)
                                              : HFv(2, b, kp - 128);
                        const float rr = 1.f / (1.f + __expf(-val));
                        hq_s[b*ASTR + kp] = f2bf(rr * hu);
                    } else {
                        const int g = lane & 3;
                        const int u = (kp - 192) >> 2;
                        float m = fmaxf(val, __shfl_xor(val, 1, 64));
                        m = fmaxf(m, __shfl_xor(m, 2, 64));
                        float e = __expf(val - m);
                        float s = e + __shfl_xor(e, 1, 64);
                        s += __shfl_xor(s, 2, 64);
                        const float gate = e / s;
                        float hsel = 0.f;
                        if (g == 1)      hsel = HFv(1, b, u);
                        else if (g == 2) hsel = HFv(0, b, u);
                        else if (g == 3) hsel = HFv(2, b, u);
                        float tt = gate * hsel;
                        float s3 = tt + __shfl_xor(tt, 1, 64);
                        s3 += __shfl_xor(s3, 2, 64);
                        if (g == 0) { ZI_s[b*68 + u] = gate; ZH_s[b*68 + u] = s3; }
                    }
                }
            }
        }
        __syncthreads();

        // ---- phase B GEMM + epilogue ----
        {
            f32x4 acc2[2];
            acc2[0] = (f32x4){0,0,0,0}; acc2[1] = (f32x4){0,0,0,0};
            #pragma unroll
            for (int ks = 0; ks < 7; ++ks) {
                s16x8 a2 = *(const s16x8*)&hq_s[(mt*16 + col)*ASTR + ks*32 + (rowq << 1)];
                #pragma unroll
                for (int i = 0; i < 2; ++i) {
                    s16x8 bf = *(const s16x8*)&UF[(((th + i)*7 + ks)*64 + lane)*8];
                    acc2[i] = __builtin_amdgcn_mfma_f32_16x16x32_bf16(a2, bf, acc2[i], 0, 0, 0);
                }
            }
            #pragma unroll
            for (int i = 0; i < 2; ++i) {
                const int u = (th + i)*16 + col;
                const float wb = wij_b[u];
                #pragma unroll
                for (int reg = 0; reg < 4; ++reg) {
                    const int b = mt*16 + rowq + reg;
                    const float hn = tanhf(acc2[i][reg] + wb);
                    const float h = ZH_s[b*68 + u] + ZI_s[b*68 + u] * hn;
                    HFv(1, b, u) = h;                                   // hl for next step
                    if (l < 63) Hout[((size_t)(l*64 + r))*4096 + b*64 + u] = h;
                    else if (r == 63) out[b*64 + u] = h;
                }
            }
        }
        __syncthreads();   // all LDS+global writes drained (each thread vmcnt(0))

        // ---- release: publish row (l, r) ----
        if (tid == 0 && l < 63)
            __hip_atomic_store(&flags[l*64 + r], 1, __ATOMIC_RELEASE,
                               __HIP_MEMORY_SCOPE_AGENT);
    }
}

extern "C" void kernel_launch(void* const* d_in, const int* in_sizes, int n_in,
                              void* d_out, int out_size, void* d_ws, size_t ws_size,
                              hipStream_t stream)
{
    const float* inp   = (const float*)d_in[0];
    const float* wr_w  = (const float*)d_in[1];
    const float* wr_b  = (const float*)d_in[2];
    const float* wz_w  = (const float*)d_in[3];
    const float* wz_b  = (const float*)d_in[4];
    const float* wij_w = (const float*)d_in[5];
    const float* wij_b = (const float*)d_in[6];
    const float* U_w   = (const float*)d_in[7];
    float* out = (float*)d_out;

    unsigned short* WF = (unsigned short*)d_ws;
    unsigned short* UF = WF + N_WF;
    unsigned short* XT = UF + N_UF;
    float* fbase = (float*)(XT + N_XT);
    float* BAf   = fbase;                          // 512 floats
    float* Hout  = fbase + 512;                    // 64*64*4096 floats (64 MB)
    int*   flags = (int*)(Hout + (size_t)64*64*4096);  // 4096 ints

    hipMemsetAsync(flags, 0, 64*64*sizeof(int), stream);
    prep_pack<<<58, 256, 0, stream>>>(wr_w, wr_b, wz_w, wz_b, wij_w, U_w, WF, UF, BAf);
    xpose<<<dim3(128, 32), 256, 0, stream>>>(inp, XT);

    hipFuncSetAttribute((const void*)gru_persist,
                        hipFuncAttributeMaxDynamicSharedMemorySize, SMEM_BYTES);
    gru_persist<<<64, 512, SMEM_BYTES, stream>>>(WF, UF, BAf, XT, wij_b, Hout, flags, out);
}

// Round 4
// 8113.458 us; speedup vs baseline: 1.0271x; 1.0271x over previous
//
#include <hip/hip_runtime.h>
#include <math.h>

// SpatialGRU persistent-wavefront kernel. B=64, C=16, L=64, R=64, U=64, D=208.
// 64 persistent blocks, block = grid row l; cells (l, r=0..63) sequential.
// Cross-block dep (top row) via write-through (sc0 sc1) payload stores + flag;
// NO release fences / wbl2 in the loop. left/diag state in per-block LDS fp32.
// Phase A: [64 b x 448 kp] = hq[64x224] @ W^T   (bf16 MFMA 16x16x32)
// Phase B: [64 b x 64 u]   = P [64x224] @ U2^T  (P = rr.*hu | x)

typedef short s16x8 __attribute__((ext_vector_type(8)));
typedef float f32x4 __attribute__((ext_vector_type(4)));

#define ASTR 232                 // hq row stride (bf16 elems); 224 data + 8 pad
#define N_WF (28*7*512)          // shorts
#define N_UF (4*7*512)           // shorts
#define N_XT (4096*1024)         // shorts
#define SMEM_BYTES (64*ASTR*2 + 3*64*68*4 + 2*64*68*4)   // 116736 B

#define HFv(s,b,u)  HF[(((s)*64 + (b))*68) + (u)]

__device__ __forceinline__ unsigned short f2bf(float v) {
    unsigned int x = __float_as_uint(v);
    unsigned int r = (x + 0x7fffu + ((x >> 16) & 1u)) >> 16;
    return (unsigned short)r;
}
__device__ __forceinline__ unsigned int pack2(float a, float b) {
    return (unsigned int)f2bf(a) | ((unsigned int)f2bf(b) << 16);
}

// ---- LLC-coherent (cross-XCD) access helpers: per-access sc0 sc1 bits ----
__device__ __forceinline__ void st_llc_f32(float* p, float v) {
    asm volatile("global_store_dword %0, %1, off sc0 sc1" :: "v"(p), "v"(v) : "memory");
}
__device__ __forceinline__ void st_llc_u32(unsigned int* p, unsigned int v) {
    asm volatile("global_store_dword %0, %1, off sc0 sc1" :: "v"(p), "v"(v) : "memory");
}
__device__ __forceinline__ unsigned int ld_llc_u32(const unsigned int* p) {
    unsigned int r;
    asm volatile("global_load_dword %0, %1, off sc0 sc1\n\ts_waitcnt vmcnt(0)"
                 : "=v"(r) : "v"(p) : "memory");
    return r;
}
__device__ __forceinline__ void ld_llc_row32(const float* p, f32x4& a, f32x4& b) {
    asm volatile("global_load_dwordx4 %0, %2, off sc0 sc1\n\t"
                 "global_load_dwordx4 %1, %3, off sc0 sc1\n\t"
                 "s_waitcnt vmcnt(0)"
                 : "=&v"(a), "=&v"(b) : "v"(p), "v"(p + 4) : "memory");
}

// ---- prep: pack weights into MFMA B-fragment lane order ----
__global__ __launch_bounds__(256) void prep_pack(
    const float* __restrict__ wr_w, const float* __restrict__ wr_b,
    const float* __restrict__ wz_w, const float* __restrict__ wz_b,
    const float* __restrict__ wij_w, const float* __restrict__ U_w,
    unsigned short* __restrict__ WF, unsigned short* __restrict__ UF,
    float* __restrict__ BAf)
{
    int idx = blockIdx.x * 256 + threadIdx.x;
    if (idx < 28*7*64) {
        int frag = idx >> 6, lane = idx & 63;
        int nt = frag / 7, ks = frag % 7;
        int kp = nt*16 + (lane & 15);
        int kb = ks*32 + ((lane >> 4) << 3);
        #pragma unroll
        for (int e = 0; e < 8; ++e) {
            int k = kb + e;
            float v = 0.f;
            if (k < 208) {
                if (kp < 192) v = wr_w[kp*208 + k];
                else { int q = kp - 192; v = wz_w[((q & 3)*64 + (q >> 2))*208 + k]; }
            }
            WF[idx*8 + e] = f2bf(v);
        }
        return;
    }
    idx -= 28*7*64;
    if (idx < 4*7*64) {
        int frag = idx >> 6, lane = idx & 63;
        int t2 = frag / 7, ks = frag % 7;
        int u = t2*16 + (lane & 15);
        int kb = ks*32 + ((lane >> 4) << 3);
        #pragma unroll
        for (int e = 0; e < 8; ++e) {
            int k = kb + e;
            float v = 0.f;
            if (k < 192) v = U_w[u*192 + k];
            else if (k < 208) v = wij_w[u*16 + (k - 192)];
            UF[idx*8 + e] = f2bf(v);
        }
        return;
    }
    idx -= 4*7*64;
    if (idx < 512) {
        float v = 0.f;
        if (idx < 192) v = wr_b[idx];
        else if (idx < 448) { int q = idx - 192; v = wz_b[(q & 3)*64 + (q >> 2)]; }
        BAf[idx] = v;
    }
}

// ---- prep: transpose inputs (B,C,L,R) -> XT[(l,r)][(b,c)] bf16 ----
__global__ __launch_bounds__(256) void xpose(const float* __restrict__ inp,
                                             unsigned short* __restrict__ XT)
{
    __shared__ float tile[32][33];
    int bi = blockIdx.x;   // lr / 32
    int bj = blockIdx.y;   // bc / 32
    int tx = threadIdx.x & 31, ty = threadIdx.x >> 5;
    #pragma unroll
    for (int yy = 0; yy < 4; ++yy) {
        int bc = bj*32 + ty*4 + yy;
        tile[ty*4 + yy][tx] = inp[bc*4096 + bi*32 + tx];
    }
    __syncthreads();
    #pragma unroll
    for (int yy = 0; yy < 4; ++yy) {
        int lr = bi*32 + ty*4 + yy;
        XT[lr*1024 + bj*32 + tx] = f2bf(tile[tx][ty*4 + yy]);
    }
}

// ---- persistent wavefront ----
__global__ __launch_bounds__(512, 2) void gru_persist(
    const unsigned short* __restrict__ WF,
    const unsigned short* __restrict__ UF,
    const float* __restrict__ BAf,
    const unsigned short* __restrict__ XT,
    const float* __restrict__ wij_b,
    float* __restrict__ Hout,          // [l][r][b][u] fp32
    unsigned int* __restrict__ flags,  // [l][r]
    float* __restrict__ out)
{
    extern __shared__ char smem[];
    unsigned short* hq_s = (unsigned short*)smem;            // [64][ASTR] bf16
    float* HF = (float*)(smem + 64*ASTR*2);                  // [3][64][68]: ht/hl/hd fp32
    float* ZH_s = HF + 3*64*68;                              // [64][68]
    float* ZI_s = ZH_s + 64*68;                              // [64][68]

    const int tid = threadIdx.x;
    // XCD-swizzle: 8 consecutive rows per XCD (adjacent-row flag hops stay local)
    const int l = ((blockIdx.x & 7) << 3) | (blockIdx.x >> 3);

    // init: HF zero; hq K-pad cols [208,232) zero
    for (int i = tid; i < 3*64*68; i += 512) HF[i] = 0.f;
    for (int i = tid; i < 64*24; i += 512) { int b = i/24, c = 208 + (i % 24); hq_s[b*ASTR + c] = 0; }

    const int wv = tid >> 6, lane = tid & 63;
    const int col = lane & 15, rowq = (lane >> 4) << 2;
    const int sb = tid >> 3, su = (tid & 7) * 8;             // staging ownership
    const int nh = wv & 3, mh = wv >> 2;                     // phase A tile
    const int mt = wv >> 1, th = (wv & 1) * 2;               // phase B tile

    for (int r = 0; r < 64; ++r) {
        // ---- staging part 1 (no top-row dependency): hd <- old ht; hl; x ----
        {
            float oht[8], hl8[8];
            #pragma unroll
            for (int e = 0; e < 8; ++e) oht[e] = HFv(0, sb, su + e);
            #pragma unroll
            for (int e = 0; e < 8; ++e) hl8[e] = HFv(1, sb, su + e);
            #pragma unroll
            for (int e = 0; e < 8; ++e) HFv(2, sb, su + e) = oht[e];
            #pragma unroll
            for (int e = 0; e < 8; e += 2) {
                *(unsigned int*)&hq_s[sb*ASTR +  64 + su + e] = pack2(hl8[e], hl8[e+1]); // hl
                *(unsigned int*)&hq_s[sb*ASTR + 128 + su + e] = pack2(oht[e], oht[e+1]); // hd
            }
            if (su < 16) {   // x: 2 threads per b row, 8 shorts each
                const unsigned short* xs = XT + ((size_t)(l*64 + r))*1024 + sb*16 + su;
                #pragma unroll
                for (int e = 0; e < 8; e += 2)
                    *(unsigned int*)&hq_s[sb*ASTR + 192 + su + e] = *(const unsigned int*)&xs[e];
            }
        }

        // ---- wait for top row (l-1, r) ----
        if (l > 0 && tid == 0) {
            while (ld_llc_u32(&flags[(l-1)*64 + r]) == 0u)
                __builtin_amdgcn_s_sleep(1);
        }
        __syncthreads();

        // ---- staging part 2: ht <- row (l-1, r) via LLC loads ----
        {
            float nht[8];
            if (l > 0) {
                const float* Hrow = Hout + ((size_t)((l-1)*64 + r))*4096 + sb*64 + su;
                f32x4 a, b4;
                ld_llc_row32(Hrow, a, b4);
                nht[0]=a[0]; nht[1]=a[1]; nht[2]=a[2]; nht[3]=a[3];
                nht[4]=b4[0]; nht[5]=b4[1]; nht[6]=b4[2]; nht[7]=b4[3];
            } else {
                #pragma unroll
                for (int e = 0; e < 8; ++e) nht[e] = 0.f;
            }
            #pragma unroll
            for (int e = 0; e < 8; ++e) HFv(0, sb, su + e) = nht[e];
            #pragma unroll
            for (int e = 0; e < 8; e += 2)
                *(unsigned int*)&hq_s[sb*ASTR + su + e] = pack2(nht[e], nht[e+1]);       // ht
        }
        __syncthreads();

        // ---- phase A GEMM: 2 M-tiles x 7 N-tiles x 7 K ----
        f32x4 acc[7][2];
        #pragma unroll
        for (int t = 0; t < 7; ++t) { acc[t][0] = (f32x4){0,0,0,0}; acc[t][1] = (f32x4){0,0,0,0}; }
        #pragma unroll
        for (int ks = 0; ks < 7; ++ks) {
            s16x8 af0 = *(const s16x8*)&hq_s[(mh*32 + col)*ASTR + ks*32 + (rowq << 1)];
            s16x8 af1 = *(const s16x8*)&hq_s[(mh*32 + 16 + col)*ASTR + ks*32 + (rowq << 1)];
            #pragma unroll
            for (int t = 0; t < 7; ++t) {
                s16x8 bf = *(const s16x8*)&WF[(((nh*7 + t)*7 + ks)*64 + lane)*8];
                acc[t][0] = __builtin_amdgcn_mfma_f32_16x16x32_bf16(af0, bf, acc[t][0], 0, 0, 0);
                acc[t][1] = __builtin_amdgcn_mfma_f32_16x16x32_bf16(af1, bf, acc[t][1], 0, 0, 0);
            }
        }
        __syncthreads();

        // ---- activations: rr -> P (overwrite hq cols 0..191); z -> gates ----
        #pragma unroll
        for (int t = 0; t < 7; ++t) {
            const int kp = (nh*7 + t)*16 + col;
            const float bias = BAf[kp];
            const bool isrr = kp < 192;
            #pragma unroll
            for (int mti = 0; mti < 2; ++mti) {
                #pragma unroll
                for (int reg = 0; reg < 4; ++reg) {
                    const int b = (mh*2 + mti)*16 + rowq + reg;
                    const float val = acc[t][mti][reg] + bias;
                    if (isrr) {
                        float hu = (kp < 64)  ? HFv(1, b, kp)
                                 : (kp < 128) ? HFv(0, b, kp - 64)
                                              : HFv(2, b, kp - 128);
                        const float rr = 1.f / (1.f + __expf(-val));
                        hq_s[b*ASTR + kp] = f2bf(rr * hu);
                    } else {
                        const int g = lane & 3;
                        const int u = (kp - 192) >> 2;
                        float m = fmaxf(val, __shfl_xor(val, 1, 64));
                        m = fmaxf(m, __shfl_xor(m, 2, 64));
                        float e = __expf(val - m);
                        float s = e + __shfl_xor(e, 1, 64);
                        s += __shfl_xor(s, 2, 64);
                        const float gate = e / s;
                        float hsel = 0.f;
                        if (g == 1)      hsel = HFv(1, b, u);
                        else if (g == 2) hsel = HFv(0, b, u);
                        else if (g == 3) hsel = HFv(2, b, u);
                        float tt = gate * hsel;
                        float s3 = tt + __shfl_xor(tt, 1, 64);
                        s3 += __shfl_xor(s3, 2, 64);
                        if (g == 0) { ZI_s[b*68 + u] = gate; ZH_s[b*68 + u] = s3; }
                    }
                }
            }
        }
        __syncthreads();

        // ---- phase B GEMM + epilogue ----
        {
            f32x4 acc2[2];
            acc2[0] = (f32x4){0,0,0,0}; acc2[1] = (f32x4){0,0,0,0};
            #pragma unroll
            for (int ks = 0; ks < 7; ++ks) {
                s16x8 a2 = *(const s16x8*)&hq_s[(mt*16 + col)*ASTR + ks*32 + (rowq << 1)];
                #pragma unroll
                for (int i = 0; i < 2; ++i) {
                    s16x8 bf = *(const s16x8*)&UF[(((th + i)*7 + ks)*64 + lane)*8];
                    acc2[i] = __builtin_amdgcn_mfma_f32_16x16x32_bf16(a2, bf, acc2[i], 0, 0, 0);
                }
            }
            float* Hrow = Hout + ((size_t)(l*64 + r))*4096;
            #pragma unroll
            for (int i = 0; i < 2; ++i) {
                const int u = (th + i)*16 + col;
                const float wb = wij_b[u];
                #pragma unroll
                for (int reg = 0; reg < 4; ++reg) {
                    const int b = mt*16 + rowq + reg;
                    const float hn = tanhf(acc2[i][reg] + wb);
                    const float h = ZH_s[b*68 + u] + ZI_s[b*68 + u] * hn;
                    HFv(1, b, u) = h;                                   // hl for next step
                    if (l < 63) st_llc_f32(&Hrow[b*64 + u], h);         // write-through to LLC
                    else if (r == 63) out[b*64 + u] = h;
                }
            }
        }
        // barrier: every thread has drained vmcnt(0) (its sc1 stores are LLC-visible)
        __syncthreads();

        // ---- publish row (l, r): plain sc1 dword, no fence ----
        if (tid == 0 && l < 63)
            st_llc_u32(&flags[l*64 + r], 1u);
    }
}

extern "C" void kernel_launch(void* const* d_in, const int* in_sizes, int n_in,
                              void* d_out, int out_size, void* d_ws, size_t ws_size,
                              hipStream_t stream)
{
    const float* inp   = (const float*)d_in[0];
    const float* wr_w  = (const float*)d_in[1];
    const float* wr_b  = (const float*)d_in[2];
    const float* wz_w  = (const float*)d_in[3];
    const float* wz_b  = (const float*)d_in[4];
    const float* wij_w = (const float*)d_in[5];
    const float* wij_b = (const float*)d_in[6];
    const float* U_w   = (const float*)d_in[7];
    float* out = (float*)d_out;

    unsigned short* WF = (unsigned short*)d_ws;
    unsigned short* UF = WF + N_WF;
    unsigned short* XT = UF + N_UF;
    float* fbase = (float*)(XT + N_XT);
    float* BAf   = fbase;                          // 512 floats
    float* Hout  = fbase + 512;                    // 64*64*4096 floats (64 MB)
    unsigned int* flags = (unsigned int*)(Hout + (size_t)64*64*4096);  // 4096 ints

    hipMemsetAsync(flags, 0, 64*64*sizeof(unsigned int), stream);
    prep_pack<<<58, 256, 0, stream>>>(wr_w, wr_b, wz_w, wz_b, wij_w, U_w, WF, UF, BAf);
    xpose<<<dim3(128, 32), 256, 0, stream>>>(inp, XT);

    hipFuncSetAttribute((const void*)gru_persist,
                        hipFuncAttributeMaxDynamicSharedMemorySize, SMEM_BYTES);
    gru_persist<<<64, 512, SMEM_BYTES, stream>>>(WF, UF, BAf, XT, wij_b, Hout, flags, out);
}